// Round 5
// baseline (913.404 us; speedup 1.0000x reference)
//
#include <hip/hip_runtime.h>

typedef __bf16 bf16x8 __attribute__((ext_vector_type(8)));
typedef float f32x4 __attribute__((ext_vector_type(4)));
typedef float f32x16 __attribute__((ext_vector_type(16)));
typedef unsigned uint2e __attribute__((ext_vector_type(2)));

#define SCLOG 0.04508422f   // (1024^-0.5) * log2(e)

// ---------- helpers ----------
__device__ __forceinline__ unsigned short f2bf(float f) {
  union { float f; unsigned int u; } v;
  v.f = f;
  unsigned int u = v.u;
  u += 0x7fffu + ((u >> 16) & 1u);   // RNE
  return (unsigned short)(u >> 16);
}

__device__ __forceinline__ void gld_lds16(const void* g, void* l) {
  __builtin_amdgcn_global_load_lds(
      (const __attribute__((address_space(1))) void*)g,
      (__attribute__((address_space(3))) void*)l, 16, 0, 0);
}

// ---------- kernel 1: fp32 -> bf16 conversion ----------
__global__ __launch_bounds__(256) void convert_kernel(
    const float* __restrict__ q, const float* __restrict__ k,
    const float* __restrict__ wq, const float* __restrict__ wk,
    const float* __restrict__ wv, const float* __restrict__ wp,
    unsigned short* __restrict__ qb, unsigned short* __restrict__ kb,
    unsigned short* __restrict__ Wqkv, unsigned short* __restrict__ Wpb) {
  size_t i = (size_t)blockIdx.x * 256 + threadIdx.x;
  const float* src; unsigned short* dst; size_t off;
  if (i < 4194304)      { src = q;  dst = qb;             off = i; }
  else if (i < 8388608) { src = k;  dst = kb;             off = i - 4194304; }
  else if (i < 8650752) { src = wq; dst = Wqkv;           off = i - 8388608; }
  else if (i < 8912896) { src = wk; dst = Wqkv + 1048576; off = i - 8650752; }
  else if (i < 9175040) { src = wv; dst = Wqkv + 2097152; off = i - 8912896; }
  else                  { src = wp; dst = Wpb;            off = i - 9175040; }
  float4 v = ((const float4*)src)[off];
  ushort4 o;
  o.x = f2bf(v.x); o.y = f2bf(v.y); o.z = f2bf(v.z); o.w = f2bf(v.w);
  ((ushort4*)dst)[off] = o;
}

// ---------- kernel 2: fused QKV GEMM, 256x256 tile, BK=64, 8-phase ----------
// Q output pre-scaled by SCLOG (softmax scale folded into Q).
#define QKV_BAR __builtin_amdgcn_s_barrier()
#define QKV_LGKM asm volatile("s_waitcnt lgkmcnt(0)" ::: "memory")

#define QKV_STG(lc, h, srcb, s)                                               \
  gld_lds16((srcb) + (size_t)(s) * 128 + gro0, (lc) + (h) * 16384 + d0);      \
  gld_lds16((srcb) + (size_t)(s) * 128 + gro1, (lc) + (h) * 16384 + d0 + 1024);

#define QKV_RDA(I0)                                                           \
  _Pragma("unroll") for (int i4 = 0; i4 < 4; ++i4) {                          \
    af[i4][0] = *(const bf16x8*)(tb + rbA + ((I0) + i4) * 2048 + cx0);        \
    af[i4][1] = *(const bf16x8*)(tb + rbA + ((I0) + i4) * 2048 + cx1);        \
  }

#define QKV_RDB(JP)                                                           \
  _Pragma("unroll") for (int j2 = 0; j2 < 2; ++j2) {                          \
    bfr[JP][j2][0] = *(const bf16x8*)(tb + rbB + ((JP) * 2 + j2) * 2048 + cx0); \
    bfr[JP][j2][1] = *(const bf16x8*)(tb + rbB + ((JP) * 2 + j2) * 2048 + cx1); \
  }

#define QKV_MM(I0, JP)                                                        \
  _Pragma("unroll") for (int i4 = 0; i4 < 4; ++i4)                            \
  _Pragma("unroll") for (int j2 = 0; j2 < 2; ++j2)                            \
  _Pragma("unroll") for (int kk = 0; kk < 2; ++kk)                            \
    acc[(I0) + i4][(JP) * 2 + j2] = __builtin_amdgcn_mfma_f32_16x16x32_bf16(  \
        af[i4][kk], bfr[JP][j2][kk], acc[(I0) + i4][(JP) * 2 + j2], 0, 0, 0);

__global__ __launch_bounds__(512, 2) void gemm_qkv8_kernel(
    const unsigned short* __restrict__ qb,
    const unsigned short* __restrict__ kb,
    const unsigned short* __restrict__ W,       // [3072][1024]
    unsigned short* __restrict__ Qo,
    unsigned short* __restrict__ Ko,
    unsigned short* __restrict__ Vo) {
  __shared__ char lds[131072];

  const int t = threadIdx.x;
  const int lane = t & 63;
  const int w = t >> 6;
  const int fr = lane & 15;
  const int quad = lane >> 4;

  const int orig = blockIdx.x;
  const int sseq = orig >> 3;
  const int tn = sseq >> 3;
  const int tm = (orig & 7) * 8 + (sseq & 7);

  const unsigned short* Ap = (tn < 4) ? qb : kb;
  const char* aBase = (const char*)Ap + (size_t)(tm * 256) * 2048;
  const char* bBase = (const char*)W + (size_t)(tn * 256) * 2048;

  const int wm2 = w >> 2, wn4 = w & 3;

  const size_t gro0 = (size_t)(w * 16 + (lane >> 3)) * 2048 + (size_t)(((lane & 7) ^ (lane >> 3)) << 4);
  const size_t gro1 = gro0 + 8 * 2048;
  const int d0 = w * 2048 + lane * 16;

  const int rbA = (wm2 * 128 + fr) * 128;
  const int rbB = 32768 + (wn4 * 64 + fr) * 128;
  const int cx0 = (quad * 16) ^ ((fr & 7) << 4);
  const int cx1 = cx0 ^ 64;

  f32x4 acc[8][4];
#pragma unroll
  for (int i = 0; i < 8; ++i)
#pragma unroll
    for (int j = 0; j < 4; ++j) acc[i][j] = (f32x4){0.f, 0.f, 0.f, 0.f};

#pragma unroll
  for (int s = 0; s < 2; ++s) {
    char* lc = lds + s * 65536;
    QKV_STG(lc, 0, aBase, s);
    QKV_STG(lc, 1, aBase + 262144, s);
    QKV_STG(lc + 32768, 0, bBase, s);
    QKV_STG(lc + 32768, 1, bBase + 262144, s);
  }
  asm volatile("s_waitcnt vmcnt(8)" ::: "memory");
  QKV_BAR;

#pragma unroll 1
  for (int kt = 0; kt < 16; ++kt) {
    const char* tb = lds + (kt & 1) * 65536;
    char* lc = lds + (kt & 1) * 65536;
    const int s = kt + 2;
    bf16x8 af[4][2], bfr[2][2][2];

    QKV_RDA(0);
    QKV_RDB(0);
    QKV_BAR; QKV_LGKM;
    __builtin_amdgcn_s_setprio(1);
    QKV_MM(0, 0);
    __builtin_amdgcn_s_setprio(0);
    QKV_BAR;

    QKV_RDB(1);
    QKV_BAR; QKV_LGKM;
    __builtin_amdgcn_s_setprio(1);
    QKV_MM(0, 1);
    __builtin_amdgcn_s_setprio(0);
    QKV_BAR;

    QKV_RDA(4);
    if (s < 16) {
      QKV_STG(lc + 32768, 0, bBase, s);
      QKV_STG(lc + 32768, 1, bBase + 262144, s);
    }
    QKV_BAR; QKV_LGKM;
    __builtin_amdgcn_s_setprio(1);
    QKV_MM(4, 1);
    __builtin_amdgcn_s_setprio(0);
    QKV_BAR;

    if (s < 16) {
      QKV_STG(lc, 0, aBase, s);
      QKV_STG(lc, 1, aBase + 262144, s);
    }
    QKV_BAR;
    __builtin_amdgcn_s_setprio(1);
    QKV_MM(4, 0);
    __builtin_amdgcn_s_setprio(0);
    if (kt <= 13)      { asm volatile("s_waitcnt vmcnt(8)" ::: "memory"); }
    else if (kt == 14) { asm volatile("s_waitcnt vmcnt(0)" ::: "memory"); }
    if (kt < 15) QKV_BAR;
  }

  const int sel = tn >> 2;  // 0=Q 1=K 2=V
  unsigned short* Out = sel == 0 ? Qo : (sel == 1 ? Ko : Vo);
  const float osc = (sel == 0) ? SCLOG : 1.f;
  const int row0 = tm * 256 + wm2 * 128 + quad * 4;
  const int col0 = (tn & 3) * 256 + wn4 * 64 + fr;
#pragma unroll
  for (int i = 0; i < 8; ++i)
#pragma unroll
    for (int j = 0; j < 4; ++j)
#pragma unroll
      for (int r = 0; r < 4; ++r)
        Out[(size_t)(row0 + i * 16 + r) * 1024 + col0 + j * 16] = f2bf(acc[i][j][r] * osc);
}

// ---------- kernel 3: per-group V transpose ----------
__global__ __launch_bounds__(256) void vtrans_kernel(
    const unsigned short* __restrict__ V, unsigned short* __restrict__ Vt) {
  __shared__ unsigned short T[128 * 136];
  const int g  = blockIdx.x >> 4;
  const int kt = blockIdx.x & 15;
  const unsigned short* Vg = V + (size_t)g * 262144 + (size_t)kt * 128 * 128;
  unsigned short* Vtg = Vt + (size_t)g * 262144 + kt * 128;
  const int t = threadIdx.x;
#pragma unroll
  for (int it = 0; it < 8; it++) {
    int seg = t + it * 256;
    int k  = seg >> 4;
    int c8 = (seg & 15) << 3;
    uint4 a = *(const uint4*)(Vg + k * 128 + c8);
    unsigned short* Tp = &T[c8 * 136 + k];
    Tp[0 * 136] = (unsigned short)(a.x & 0xffff);
    Tp[1 * 136] = (unsigned short)(a.x >> 16);
    Tp[2 * 136] = (unsigned short)(a.y & 0xffff);
    Tp[3 * 136] = (unsigned short)(a.y >> 16);
    Tp[4 * 136] = (unsigned short)(a.z & 0xffff);
    Tp[5 * 136] = (unsigned short)(a.z >> 16);
    Tp[6 * 136] = (unsigned short)(a.w & 0xffff);
    Tp[7 * 136] = (unsigned short)(a.w >> 16);
  }
  __syncthreads();
#pragma unroll
  for (int it = 0; it < 8; it++) {
    int seg = t + it * 256;
    int c  = seg >> 4;
    int k8 = (seg & 15) << 3;
    uint4 o = *(const uint4*)&T[c * 136 + k8];
    *(uint4*)(Vtg + (size_t)c * 2048 + k8) = o;
  }
}

// ---------- kernel 4 v5: flash attention, 32x32 MFMA, in-register P ----------
// 8 waves x 32 qrows = 256-row Q tile; KV tile 64 keys; K/V dbuf in LDS (64KB).
// S^T = mfma32x32(K, Q^T): lane holds full P row for qrow=lane&31 -> softmax
// in-lane; PV A-frags rebuilt in-register via 16 cvt_pk + 8 permlane32_swap.
// No P in LDS. LDS bytes/FLOP halved vs v4 (32 qrows amortize K/V reads).
#define PACK_HALF(EX, KSBASE)                                                  \
    _Pragma("unroll")                                                          \
    for (int c2 = 0; c2 < 2; c2++)                                             \
      _Pragma("unroll")                                                        \
      for (int e = 0; e < 2; e++) {                                            \
        unsigned ua, ub;                                                       \
        asm("v_cvt_pk_bf16_f32 %0, %1, %2" : "=v"(ua)                          \
            : "v"(EX[8 * c2 + 2 * e]), "v"(EX[8 * c2 + 2 * e + 1]));           \
        asm("v_cvt_pk_bf16_f32 %0, %1, %2" : "=v"(ub)                          \
            : "v"(EX[8 * c2 + 4 + 2 * e]), "v"(EX[8 * c2 + 4 + 2 * e + 1]));   \
        uint2e rr = __builtin_amdgcn_permlane32_swap(ua, ub, false, false);    \
        if (e == 0) { paw[(KSBASE) + c2].x = rr[0]; paw[(KSBASE) + c2].z = rr[1]; } \
        else        { paw[(KSBASE) + c2].y = rr[0]; paw[(KSBASE) + c2].w = rr[1]; } \
      }

#define ATTN_TILE(KSH, VSH, KST, VST, PREF)                                    \
  {                                                                            \
    if (PREF) {                                                                \
      gld_lds16(kp + kS0, (KST) + kD0);                                        \
      gld_lds16(kp + kS1, (KST) + kD1);                                        \
      gld_lds16(vp + vS0, (VST) + vD0);                                        \
      gld_lds16(vp + vS1, (VST) + vD1);                                        \
      kp += 8192; vp += 64;                                                    \
    }                                                                          \
    f32x16 s0, s1;                                                             \
    _Pragma("unroll")                                                          \
    for (int r = 0; r < 16; r++) { s0[r] = 0.f; s1[r] = 0.f; }                 \
    {                                                                          \
      bf16x8 kf[8];                                                            \
      _Pragma("unroll")                                                        \
      for (int ks = 0; ks < 8; ks++)                                           \
        kf[ks] = *(const bf16x8*)((KSH) + kb0 + kOf[ks]);                      \
      _Pragma("unroll")                                                        \
      for (int ks = 0; ks < 8; ks++)                                           \
        s0 = __builtin_amdgcn_mfma_f32_32x32x16_bf16(kf[ks], qf[ks], s0, 0, 0, 0); \
    }                                                                          \
    {                                                                          \
      bf16x8 kf[8];                                                            \
      _Pragma("unroll")                                                        \
      for (int ks = 0; ks < 8; ks++)                                           \
        kf[ks] = *(const bf16x8*)((KSH) + kb0 + 8192 + kOf[ks]);               \
      _Pragma("unroll")                                                        \
      for (int ks = 0; ks < 8; ks++)                                           \
        s1 = __builtin_amdgcn_mfma_f32_32x32x16_bf16(kf[ks], qf[ks], s1, 0, 0, 0); \
    }                                                                          \
    float ex0[16], ex1[16];                                                    \
    _Pragma("unroll")                                                          \
    for (int r = 0; r < 16; r++) {                                             \
      ex0[r] = __builtin_amdgcn_exp2f(fminf(s0[r], 30.f));                     \
      ex1[r] = __builtin_amdgcn_exp2f(fminf(s1[r], 30.f));                     \
      lp += ex0[r] + ex1[r];                                                   \
    }                                                                          \
    uint4 paw[4];                                                              \
    PACK_HALF(ex0, 0)                                                          \
    PACK_HALF(ex1, 2)                                                          \
    _Pragma("unroll")                                                          \
    for (int cb = 0; cb < 4; cb++) {                                           \
      _Pragma("unroll")                                                        \
      for (int ks = 0; ks < 4; ks++) {                                         \
        bf16x8 vf = *(const bf16x8*)((VSH) + cb * 4096 + vOf[ks]);             \
        bf16x8 pa8 = __builtin_bit_cast(bf16x8, paw[ks]);                      \
        O[cb] = __builtin_amdgcn_mfma_f32_32x32x16_bf16(pa8, vf, O[cb], 0, 0, 0); \
      }                                                                        \
    }                                                                          \
    __syncthreads();                                                           \
  }

__global__ __launch_bounds__(512, 4) void attn_kernel(
    const unsigned short* __restrict__ Q,
    const unsigned short* __restrict__ K,
    const unsigned short* __restrict__ Vt,   // bf16 [64 grp][128 chunk][2048 key]
    unsigned short* __restrict__ ctx) {
  // LDS 64KB: Kbuf[b]=smem+b*16384 [64 key][256B swz]; Vbuf[b]=smem+32768+b*16384
  // [128 chunk][128B swz]. Q staged through smem[0..64K) in prologue only.
  __shared__ unsigned char smem[65536];

  const int bid = blockIdx.x;
  const int g  = (bid & 7) * 8 + (bid >> 6);     // bijective XCD swizzle (512=8*64)
  const int qt = (bid >> 3) & 7;
  const unsigned short* Qg = Q + (size_t)g * 262144 + (size_t)qt * 32768;
  const unsigned short* Kg = K + (size_t)g * 262144;
  const unsigned short* Vg = Vt + (size_t)g * 262144;   // [128][2048]

  const int t    = threadIdx.x;
  const int lane = t & 63;
  const int wv   = t >> 6;          // wave owns qrows [wv*32, wv*32+32)
  const int col  = lane & 31;
  const int hi   = lane >> 5;
  const int qrow = wv * 32 + col;

  // loop-invariant swizzled LDS offsets
  int kOf[8];
#pragma unroll
  for (int ks = 0; ks < 8; ks++) {
    int c = ks * 2 + hi;
    kOf[ks] = ((c & 8) | ((c ^ (col & 7)) & 7)) << 4;
  }
  const int kb0 = col * 256;
  int vOf[4];
#pragma unroll
  for (int ks = 0; ks < 4; ks++) {
    int c = ks * 2 + hi;
    vOf[ks] = col * 128 + (((c ^ (col & 7)) & 7) << 4);
  }
  int kS0, kS1, kD0, kD1, vS0, vS1, vD0, vD1;
  {
    int seg0 = t, seg1 = t + 512;
    int r0 = seg0 >> 4, p0 = seg0 & 15, c0 = (p0 & 8) | ((p0 ^ r0) & 7);
    int r1 = seg1 >> 4, p1 = seg1 & 15, c1 = (p1 & 8) | ((p1 ^ r1) & 7);
    kS0 = r0 * 128 + c0 * 8;  kD0 = seg0 * 16;
    kS1 = r1 * 128 + c1 * 8;  kD1 = seg1 * 16;
    int vr0 = seg0 >> 3, vp0 = seg0 & 7, vc0 = vp0 ^ (vr0 & 7);
    int vr1 = seg1 >> 3, vp1 = seg1 & 7, vc1 = vp1 ^ (vr1 & 7);
    vS0 = vr0 * 2048 + vc0 * 8;  vD0 = seg0 * 16;
    vS1 = vr1 * 2048 + vc1 * 8;  vD1 = seg1 * 16;
  }

  // stage Q [256 rows x 256B] swizzled into smem[0..65536)
#pragma unroll
  for (int it = 0; it < 8; it++) {
    int seg = t + it * 512;
    int r = seg >> 4, p = seg & 15;
    int c = (p & 8) | ((p ^ r) & 7);
    gld_lds16(Qg + r * 128 + c * 8, smem + seg * 16);
  }
  __syncthreads();
  bf16x8 qf[8];   // B-frag: Q[qrow=col][d = ks*16 + hi*8 + j]  (pre-scaled)
#pragma unroll
  for (int ks = 0; ks < 8; ks++) {
    int c = ks * 2 + hi;
    int p = (c & 8) | ((c ^ (qrow & 7)) & 7);
    qf[ks] = *(const bf16x8*)(smem + qrow * 256 + p * 16);
  }
  __syncthreads();   // all waves done reading Q (K/V bufs overlay it)

  // prologue: stage tile 0 into buffer 0
  gld_lds16(Kg + kS0, smem + kD0);
  gld_lds16(Kg + kS1, smem + kD1);
  gld_lds16(Vg + vS0, smem + 32768 + vD0);
  gld_lds16(Vg + vS1, smem + 32768 + vD1);
  __syncthreads();

  const unsigned short* kp = Kg + 8192;   // tile 1
  const unsigned short* vp = Vg + 64;     // tile 1

  f32x16 O[4];   // D[qrow(reg)][chunk = cb*32+col]
#pragma unroll
  for (int cb = 0; cb < 4; cb++)
#pragma unroll
    for (int r = 0; r < 16; r++) O[cb][r] = 0.f;
  float lp = 0.f;

  unsigned char* B0K = smem;
  unsigned char* B1K = smem + 16384;
  unsigned char* B0V = smem + 32768;
  unsigned char* B1V = smem + 49152;

#pragma unroll 1
  for (int kt2 = 0; kt2 < 16; kt2++) {
    ATTN_TILE(B0K, B0V, B1K, B1V, 1);
    ATTN_TILE(B1K, B1V, B0K, B0V, (kt2 < 15));
  }

  // lp currently = sum over this lane's 32 keys/tile; pair-lane holds the rest
  lp += __shfl_xor(lp, 32);
  float* linv_arr = (float*)smem;   // K/V dead after final barrier
  linv_arr[wv * 32 + col] = 1.f / lp;
  float4 li[4];
#pragma unroll
  for (int rq = 0; rq < 4; rq++)
    li[rq] = *(const float4*)&linv_arr[wv * 32 + rq * 8 + hi * 4];

  unsigned short* Cg = ctx + (size_t)g * 262144 + (size_t)qt * 32768;
#pragma unroll
  for (int cb = 0; cb < 4; cb++)
#pragma unroll
    for (int rq = 0; rq < 4; rq++)
#pragma unroll
      for (int j = 0; j < 4; j++) {
        int row = wv * 32 + rq * 8 + hi * 4 + j;
        Cg[(size_t)row * 128 + cb * 32 + col] = f2bf(O[cb][rq * 4 + j] * li[rq][j]);
      }
}

// ---------- kernel 5: output projection + bias + residual ----------
__global__ __launch_bounds__(256) void gemm_proj_kernel(
    const unsigned short* __restrict__ A,
    const unsigned short* __restrict__ W,
    const float* __restrict__ bp,
    const float* __restrict__ qres,
    float* __restrict__ out) {
  __shared__ unsigned short Alds[128 * 32];
  __shared__ unsigned short Blds[128 * 32];
  const int t   = threadIdx.x;
  const int bid = blockIdx.x;
  const int tn  = bid % 8;
  const int tm  = bid / 8;
  const unsigned short* Bptr = W + (size_t)tn * 128 * 1024;

  const int lane = t & 63;
  const int wv   = t >> 6;
  const int wm   = (wv >> 1) * 64;
  const int wn   = (wv & 1) * 64;
  const int fr   = lane & 15;
  const int kq   = (lane >> 4) * 8;

  f32x4 acc[4][4];
#pragma unroll
  for (int i = 0; i < 4; i++)
#pragma unroll
    for (int j = 0; j < 4; j++) acc[i][j] = (f32x4){0.f, 0.f, 0.f, 0.f};

  const int sr = t >> 2;
  const int sc = (t & 3) << 3;
  const unsigned short* gA = A + (size_t)(tm * 128 + sr) * 1024 + sc;
  const unsigned short* gB = Bptr + (size_t)sr * 1024 + sc;
  unsigned short* lA = Alds + t * 8;
  unsigned short* lB = Blds + t * 8;

  for (int k0 = 0; k0 < 1024; k0 += 32) {
    gld_lds16(gA, lA);
    gld_lds16(gA + 64 * 1024, lA + 64 * 32);
    gld_lds16(gB, lB);
    gld_lds16(gB + 64 * 1024, lB + 64 * 32);
    gA += 32; gB += 32;
    __syncthreads();
    bf16x8 af[4], bfr[4];
#pragma unroll
    for (int i = 0; i < 4; i++) {
      af[i]  = *(const bf16x8*)&Alds[(wm + i * 16 + fr) * 32 + kq];
      bfr[i] = *(const bf16x8*)&Blds[(wn + i * 16 + fr) * 32 + kq];
    }
#pragma unroll
    for (int i = 0; i < 4; i++)
#pragma unroll
      for (int j = 0; j < 4; j++)
        acc[i][j] = __builtin_amdgcn_mfma_f32_16x16x32_bf16(af[i], bfr[j], acc[i][j], 0, 0, 0);
    __syncthreads();
  }

  const int quad = lane >> 4;
  const int cc   = lane & 15;
#pragma unroll
  for (int i = 0; i < 4; i++)
#pragma unroll
    for (int j = 0; j < 4; j++)
#pragma unroll
      for (int r = 0; r < 4; r++) {
        int row = tm * 128 + wm + i * 16 + quad * 4 + r;
        int col = tn * 128 + wn + j * 16 + cc;
        out[(size_t)row * 1024 + col] =
            acc[i][j][r] + bp[col] + qres[(size_t)row * 1024 + col];
      }
}

// ---------- kernel 6: in-place LayerNorm ----------
__global__ __launch_bounds__(256) void ln_kernel(float* __restrict__ out,
                                                 const float* __restrict__ gamma,
                                                 const float* __restrict__ beta) {
  __shared__ float red[8];
  const int row = blockIdx.x;
  float* p = out + (size_t)row * 1024;
  const int t = threadIdx.x;
  float4 v = ((const float4*)p)[t];
  float s  = v.x + v.y + v.z + v.w;
  float s2 = v.x * v.x + v.y * v.y + v.z * v.z + v.w * v.w;
#pragma unroll
  for (int off = 1; off < 64; off <<= 1) {
    s  += __shfl_xor(s, off);
    s2 += __shfl_xor(s2, off);
  }
  const int wv = t >> 6;
  if ((t & 63) == 0) { red[wv] = s; red[4 + wv] = s2; }
  __syncthreads();
  float S  = red[0] + red[1] + red[2] + red[3];
  float S2 = red[4] + red[5] + red[6] + red[7];
  float mu  = S * (1.f / 1024.f);
  float var = S2 * (1.f / 1024.f) - mu * mu;
  float rstd = rsqrtf(var + 1e-5f);
  float4 gm = ((const float4*)gamma)[t];
  float4 bt = ((const float4*)beta)[t];
  v.x = (v.x - mu) * rstd * gm.x + bt.x;
  v.y = (v.y - mu) * rstd * gm.y + bt.y;
  v.z = (v.z - mu) * rstd * gm.z + bt.z;
  v.w = (v.w - mu) * rstd * gm.w + bt.w;
  ((float4*)p)[t] = v;
}

// ---------- launch ----------
extern "C" void kernel_launch(void* const* d_in, const int* in_sizes, int n_in,
                              void* d_out, int out_size, void* d_ws, size_t ws_size,
                              hipStream_t stream) {
  const float* query = (const float*)d_in[0];
  const float* keys  = (const float*)d_in[1];
  const float* Wq    = (const float*)d_in[2];
  const float* Wk    = (const float*)d_in[3];
  const float* Wv    = (const float*)d_in[4];
  const float* Wp    = (const float*)d_in[5];
  const float* bp    = (const float*)d_in[6];
  const float* gamma = (const float*)d_in[7];
  const float* beta  = (const float*)d_in[8];
  float* out = (float*)d_out;

  unsigned short* ws   = (unsigned short*)d_ws;
  unsigned short* qb   = ws;                 // 16777216
  unsigned short* kb   = ws + 16777216;      // 16777216
  unsigned short* Wqkv = ws + 33554432;      // 3145728
  unsigned short* Wpb  = ws + 36700160;      // 1048576
  unsigned short* Qb   = ws + 37748736;      // 16777216
  unsigned short* Kb   = ws + 54525952;      // 16777216
  unsigned short* Vb   = ws + 71303168;      // 16777216
  unsigned short* Vtb  = kb;                 // reuse (kb dead after QKV GEMM)
  unsigned short* ctx  = qb;                 // reuse (qb dead after QKV GEMM)

  convert_kernel<<<36864, 256, 0, stream>>>(query, keys, Wq, Wk, Wv, Wp, qb, kb, Wqkv, Wpb);
  gemm_qkv8_kernel<<<768, 512, 0, stream>>>(qb, kb, Wqkv, Qb, Kb, Vb);
  vtrans_kernel<<<1024, 256, 0, stream>>>(Vb, Vtb);
  attn_kernel<<<512, 512, 0, stream>>>(Qb, Kb, Vtb, ctx);
  gemm_proj_kernel<<<1024, 256, 0, stream>>>(ctx, Wpb, bp, query, out);
  ln_kernel<<<16384, 256, 0, stream>>>(out, gamma, beta);
}

// Round 6
// 523.682 us; speedup vs baseline: 1.7442x; 1.7442x over previous
//
#include <hip/hip_runtime.h>

typedef __bf16 bf16x8 __attribute__((ext_vector_type(8)));
typedef float f32x4 __attribute__((ext_vector_type(4)));
typedef float f32x16 __attribute__((ext_vector_type(16)));
typedef unsigned uint2e __attribute__((ext_vector_type(2)));

#define SCLOG 0.04508422f   // (1024^-0.5) * log2(e)

// ---------- helpers ----------
__device__ __forceinline__ unsigned short f2bf(float f) {
  union { float f; unsigned int u; } v;
  v.f = f;
  unsigned int u = v.u;
  u += 0x7fffu + ((u >> 16) & 1u);   // RNE
  return (unsigned short)(u >> 16);
}

__device__ __forceinline__ void gld_lds16(const void* g, void* l) {
  __builtin_amdgcn_global_load_lds(
      (const __attribute__((address_space(1))) void*)g,
      (__attribute__((address_space(3))) void*)l, 16, 0, 0);
}

// ---------- kernel 1: fp32 -> bf16 conversion ----------
__global__ __launch_bounds__(256) void convert_kernel(
    const float* __restrict__ q, const float* __restrict__ k,
    const float* __restrict__ wq, const float* __restrict__ wk,
    const float* __restrict__ wv, const float* __restrict__ wp,
    unsigned short* __restrict__ qb, unsigned short* __restrict__ kb,
    unsigned short* __restrict__ Wqkv, unsigned short* __restrict__ Wpb) {
  size_t i = (size_t)blockIdx.x * 256 + threadIdx.x;
  const float* src; unsigned short* dst; size_t off;
  if (i < 4194304)      { src = q;  dst = qb;             off = i; }
  else if (i < 8388608) { src = k;  dst = kb;             off = i - 4194304; }
  else if (i < 8650752) { src = wq; dst = Wqkv;           off = i - 8388608; }
  else if (i < 8912896) { src = wk; dst = Wqkv + 1048576; off = i - 8650752; }
  else if (i < 9175040) { src = wv; dst = Wqkv + 2097152; off = i - 8912896; }
  else                  { src = wp; dst = Wpb;            off = i - 9175040; }
  float4 v = ((const float4*)src)[off];
  ushort4 o;
  o.x = f2bf(v.x); o.y = f2bf(v.y); o.z = f2bf(v.z); o.w = f2bf(v.w);
  ((ushort4*)dst)[off] = o;
}

// ---------- kernel 2: fused QKV GEMM, 256x256 tile, BK=64, 8-phase ----------
// Q output pre-scaled by SCLOG (softmax scale folded into Q).
#define QKV_BAR __builtin_amdgcn_s_barrier()
#define QKV_LGKM asm volatile("s_waitcnt lgkmcnt(0)" ::: "memory")

#define QKV_STG(lc, h, srcb, s)                                               \
  gld_lds16((srcb) + (size_t)(s) * 128 + gro0, (lc) + (h) * 16384 + d0);      \
  gld_lds16((srcb) + (size_t)(s) * 128 + gro1, (lc) + (h) * 16384 + d0 + 1024);

#define QKV_RDA(I0)                                                           \
  _Pragma("unroll") for (int i4 = 0; i4 < 4; ++i4) {                          \
    af[i4][0] = *(const bf16x8*)(tb + rbA + ((I0) + i4) * 2048 + cx0);        \
    af[i4][1] = *(const bf16x8*)(tb + rbA + ((I0) + i4) * 2048 + cx1);        \
  }

#define QKV_RDB(JP)                                                           \
  _Pragma("unroll") for (int j2 = 0; j2 < 2; ++j2) {                          \
    bfr[JP][j2][0] = *(const bf16x8*)(tb + rbB + ((JP) * 2 + j2) * 2048 + cx0); \
    bfr[JP][j2][1] = *(const bf16x8*)(tb + rbB + ((JP) * 2 + j2) * 2048 + cx1); \
  }

#define QKV_MM(I0, JP)                                                        \
  _Pragma("unroll") for (int i4 = 0; i4 < 4; ++i4)                            \
  _Pragma("unroll") for (int j2 = 0; j2 < 2; ++j2)                            \
  _Pragma("unroll") for (int kk = 0; kk < 2; ++kk)                            \
    acc[(I0) + i4][(JP) * 2 + j2] = __builtin_amdgcn_mfma_f32_16x16x32_bf16(  \
        af[i4][kk], bfr[JP][j2][kk], acc[(I0) + i4][(JP) * 2 + j2], 0, 0, 0);

__global__ __launch_bounds__(512, 2) void gemm_qkv8_kernel(
    const unsigned short* __restrict__ qb,
    const unsigned short* __restrict__ kb,
    const unsigned short* __restrict__ W,       // [3072][1024]
    unsigned short* __restrict__ Qo,
    unsigned short* __restrict__ Ko,
    unsigned short* __restrict__ Vo) {
  __shared__ char lds[131072];

  const int t = threadIdx.x;
  const int lane = t & 63;
  const int w = t >> 6;
  const int fr = lane & 15;
  const int quad = lane >> 4;

  const int orig = blockIdx.x;
  const int sseq = orig >> 3;
  const int tn = sseq >> 3;
  const int tm = (orig & 7) * 8 + (sseq & 7);

  const unsigned short* Ap = (tn < 4) ? qb : kb;
  const char* aBase = (const char*)Ap + (size_t)(tm * 256) * 2048;
  const char* bBase = (const char*)W + (size_t)(tn * 256) * 2048;

  const int wm2 = w >> 2, wn4 = w & 3;

  const size_t gro0 = (size_t)(w * 16 + (lane >> 3)) * 2048 + (size_t)(((lane & 7) ^ (lane >> 3)) << 4);
  const size_t gro1 = gro0 + 8 * 2048;
  const int d0 = w * 2048 + lane * 16;

  const int rbA = (wm2 * 128 + fr) * 128;
  const int rbB = 32768 + (wn4 * 64 + fr) * 128;
  const int cx0 = (quad * 16) ^ ((fr & 7) << 4);
  const int cx1 = cx0 ^ 64;

  f32x4 acc[8][4];
#pragma unroll
  for (int i = 0; i < 8; ++i)
#pragma unroll
    for (int j = 0; j < 4; ++j) acc[i][j] = (f32x4){0.f, 0.f, 0.f, 0.f};

#pragma unroll
  for (int s = 0; s < 2; ++s) {
    char* lc = lds + s * 65536;
    QKV_STG(lc, 0, aBase, s);
    QKV_STG(lc, 1, aBase + 262144, s);
    QKV_STG(lc + 32768, 0, bBase, s);
    QKV_STG(lc + 32768, 1, bBase + 262144, s);
  }
  asm volatile("s_waitcnt vmcnt(8)" ::: "memory");
  QKV_BAR;

#pragma unroll 1
  for (int kt = 0; kt < 16; ++kt) {
    const char* tb = lds + (kt & 1) * 65536;
    char* lc = lds + (kt & 1) * 65536;
    const int s = kt + 2;
    bf16x8 af[4][2], bfr[2][2][2];

    QKV_RDA(0);
    QKV_RDB(0);
    QKV_BAR; QKV_LGKM;
    __builtin_amdgcn_s_setprio(1);
    QKV_MM(0, 0);
    __builtin_amdgcn_s_setprio(0);
    QKV_BAR;

    QKV_RDB(1);
    QKV_BAR; QKV_LGKM;
    __builtin_amdgcn_s_setprio(1);
    QKV_MM(0, 1);
    __builtin_amdgcn_s_setprio(0);
    QKV_BAR;

    QKV_RDA(4);
    if (s < 16) {
      QKV_STG(lc + 32768, 0, bBase, s);
      QKV_STG(lc + 32768, 1, bBase + 262144, s);
    }
    QKV_BAR; QKV_LGKM;
    __builtin_amdgcn_s_setprio(1);
    QKV_MM(4, 1);
    __builtin_amdgcn_s_setprio(0);
    QKV_BAR;

    if (s < 16) {
      QKV_STG(lc, 0, aBase, s);
      QKV_STG(lc, 1, aBase + 262144, s);
    }
    QKV_BAR;
    __builtin_amdgcn_s_setprio(1);
    QKV_MM(4, 0);
    __builtin_amdgcn_s_setprio(0);
    if (kt <= 13)      { asm volatile("s_waitcnt vmcnt(8)" ::: "memory"); }
    else if (kt == 14) { asm volatile("s_waitcnt vmcnt(0)" ::: "memory"); }
    if (kt < 15) QKV_BAR;
  }

  const int sel = tn >> 2;  // 0=Q 1=K 2=V
  unsigned short* Out = sel == 0 ? Qo : (sel == 1 ? Ko : Vo);
  const float osc = (sel == 0) ? SCLOG : 1.f;
  const int row0 = tm * 256 + wm2 * 128 + quad * 4;
  const int col0 = (tn & 3) * 256 + wn4 * 64 + fr;
#pragma unroll
  for (int i = 0; i < 8; ++i)
#pragma unroll
    for (int j = 0; j < 4; ++j)
#pragma unroll
      for (int r = 0; r < 4; ++r)
        Out[(size_t)(row0 + i * 16 + r) * 1024 + col0 + j * 16] = f2bf(acc[i][j][r] * osc);
}

// ---------- kernel 3: per-group V transpose ----------
__global__ __launch_bounds__(256) void vtrans_kernel(
    const unsigned short* __restrict__ V, unsigned short* __restrict__ Vt) {
  __shared__ unsigned short T[128 * 136];
  const int g  = blockIdx.x >> 4;
  const int kt = blockIdx.x & 15;
  const unsigned short* Vg = V + (size_t)g * 262144 + (size_t)kt * 128 * 128;
  unsigned short* Vtg = Vt + (size_t)g * 262144 + kt * 128;
  const int t = threadIdx.x;
#pragma unroll
  for (int it = 0; it < 8; it++) {
    int seg = t + it * 256;
    int k  = seg >> 4;
    int c8 = (seg & 15) << 3;
    uint4 a = *(const uint4*)(Vg + k * 128 + c8);
    unsigned short* Tp = &T[c8 * 136 + k];
    Tp[0 * 136] = (unsigned short)(a.x & 0xffff);
    Tp[1 * 136] = (unsigned short)(a.x >> 16);
    Tp[2 * 136] = (unsigned short)(a.y & 0xffff);
    Tp[3 * 136] = (unsigned short)(a.y >> 16);
    Tp[4 * 136] = (unsigned short)(a.z & 0xffff);
    Tp[5 * 136] = (unsigned short)(a.z >> 16);
    Tp[6 * 136] = (unsigned short)(a.w & 0xffff);
    Tp[7 * 136] = (unsigned short)(a.w >> 16);
  }
  __syncthreads();
#pragma unroll
  for (int it = 0; it < 8; it++) {
    int seg = t + it * 256;
    int c  = seg >> 4;
    int k8 = (seg & 15) << 3;
    uint4 o = *(const uint4*)&T[c * 136 + k8];
    *(uint4*)(Vtg + (size_t)c * 2048 + k8) = o;
  }
}

// ---------- kernel 4 v6: flash attention, 32x32 MFMA, in-register P ----------
// v6 = v5 with the spill fixed: __launch_bounds__(512, 1). v5's (512,4) capped
// the allocator at 64 VGPRs vs ~180 needed -> 841 MB scratch writes, 535 us.
// 1 block/CU (8 waves, 2/SIMD) with full register budget; rounds 2-3 showed
// 2 vs 4 waves/SIMD is perf-neutral for this barrier structure.
#define PACK_HALF(EX, KSBASE)                                                  \
    _Pragma("unroll")                                                          \
    for (int c2 = 0; c2 < 2; c2++)                                             \
      _Pragma("unroll")                                                        \
      for (int e = 0; e < 2; e++) {                                            \
        unsigned ua, ub;                                                       \
        asm("v_cvt_pk_bf16_f32 %0, %1, %2" : "=v"(ua)                          \
            : "v"(EX[8 * c2 + 2 * e]), "v"(EX[8 * c2 + 2 * e + 1]));           \
        asm("v_cvt_pk_bf16_f32 %0, %1, %2" : "=v"(ub)                          \
            : "v"(EX[8 * c2 + 4 + 2 * e]), "v"(EX[8 * c2 + 4 + 2 * e + 1]));   \
        uint2e rr = __builtin_amdgcn_permlane32_swap(ua, ub, false, false);    \
        if (e == 0) { paw[(KSBASE) + c2].x = rr[0]; paw[(KSBASE) + c2].z = rr[1]; } \
        else        { paw[(KSBASE) + c2].y = rr[0]; paw[(KSBASE) + c2].w = rr[1]; } \
      }

#define ATTN_TILE(KSH, VSH, KST, VST, PREF)                                    \
  {                                                                            \
    if (PREF) {                                                                \
      gld_lds16(kp + kS0, (KST) + kD0);                                        \
      gld_lds16(kp + kS1, (KST) + kD1);                                        \
      gld_lds16(vp + vS0, (VST) + vD0);                                        \
      gld_lds16(vp + vS1, (VST) + vD1);                                        \
      kp += 8192; vp += 64;                                                    \
    }                                                                          \
    f32x16 s0, s1;                                                             \
    _Pragma("unroll")                                                          \
    for (int r = 0; r < 16; r++) { s0[r] = 0.f; s1[r] = 0.f; }                 \
    {                                                                          \
      bf16x8 kf[8];                                                            \
      _Pragma("unroll")                                                        \
      for (int ks = 0; ks < 8; ks++)                                           \
        kf[ks] = *(const bf16x8*)((KSH) + kb0 + kOf[ks]);                      \
      _Pragma("unroll")                                                        \
      for (int ks = 0; ks < 8; ks++)                                           \
        s0 = __builtin_amdgcn_mfma_f32_32x32x16_bf16(kf[ks], qf[ks], s0, 0, 0, 0); \
    }                                                                          \
    {                                                                          \
      bf16x8 kf[8];                                                            \
      _Pragma("unroll")                                                        \
      for (int ks = 0; ks < 8; ks++)                                           \
        kf[ks] = *(const bf16x8*)((KSH) + kb0 + 8192 + kOf[ks]);               \
      _Pragma("unroll")                                                        \
      for (int ks = 0; ks < 8; ks++)                                           \
        s1 = __builtin_amdgcn_mfma_f32_32x32x16_bf16(kf[ks], qf[ks], s1, 0, 0, 0); \
    }                                                                          \
    float ex0[16], ex1[16];                                                    \
    _Pragma("unroll")                                                          \
    for (int r = 0; r < 16; r++) {                                             \
      ex0[r] = __builtin_amdgcn_exp2f(fminf(s0[r], 30.f));                     \
      ex1[r] = __builtin_amdgcn_exp2f(fminf(s1[r], 30.f));                     \
      lp += ex0[r] + ex1[r];                                                   \
    }                                                                          \
    uint4 paw[4];                                                              \
    PACK_HALF(ex0, 0)                                                          \
    PACK_HALF(ex1, 2)                                                          \
    _Pragma("unroll")                                                          \
    for (int cb = 0; cb < 4; cb++) {                                           \
      _Pragma("unroll")                                                        \
      for (int ks = 0; ks < 4; ks++) {                                         \
        bf16x8 vf = *(const bf16x8*)((VSH) + cb * 4096 + vOf[ks]);             \
        bf16x8 pa8 = __builtin_bit_cast(bf16x8, paw[ks]);                      \
        O[cb] = __builtin_amdgcn_mfma_f32_32x32x16_bf16(pa8, vf, O[cb], 0, 0, 0); \
      }                                                                        \
    }                                                                          \
    __syncthreads();                                                           \
  }

__global__ __launch_bounds__(512, 1) void attn_kernel(
    const unsigned short* __restrict__ Q,
    const unsigned short* __restrict__ K,
    const unsigned short* __restrict__ Vt,   // bf16 [64 grp][128 chunk][2048 key]
    unsigned short* __restrict__ ctx) {
  // LDS 64KB: Kbuf[b]=smem+b*16384 [64 key][256B swz]; Vbuf[b]=smem+32768+b*16384
  // [128 chunk][128B swz]. Q staged through smem[0..64K) in prologue only.
  __shared__ unsigned char smem[65536];

  const int bid = blockIdx.x;
  const int g  = (bid & 7) * 8 + (bid >> 6);     // bijective XCD swizzle (512=8*64)
  const int qt = (bid >> 3) & 7;
  const unsigned short* Qg = Q + (size_t)g * 262144 + (size_t)qt * 32768;
  const unsigned short* Kg = K + (size_t)g * 262144;
  const unsigned short* Vg = Vt + (size_t)g * 262144;   // [128][2048]

  const int t    = threadIdx.x;
  const int lane = t & 63;
  const int wv   = t >> 6;          // wave owns qrows [wv*32, wv*32+32)
  const int col  = lane & 31;
  const int hi   = lane >> 5;
  const int qrow = wv * 32 + col;

  // loop-invariant swizzled LDS offsets
  int kOf[8];
#pragma unroll
  for (int ks = 0; ks < 8; ks++) {
    int c = ks * 2 + hi;
    kOf[ks] = ((c & 8) | ((c ^ (col & 7)) & 7)) << 4;
  }
  const int kb0 = col * 256;
  int vOf[4];
#pragma unroll
  for (int ks = 0; ks < 4; ks++) {
    int c = ks * 2 + hi;
    vOf[ks] = col * 128 + (((c ^ (col & 7)) & 7) << 4);
  }
  int kS0, kS1, kD0, kD1, vS0, vS1, vD0, vD1;
  {
    int seg0 = t, seg1 = t + 512;
    int r0 = seg0 >> 4, p0 = seg0 & 15, c0 = (p0 & 8) | ((p0 ^ r0) & 7);
    int r1 = seg1 >> 4, p1 = seg1 & 15, c1 = (p1 & 8) | ((p1 ^ r1) & 7);
    kS0 = r0 * 128 + c0 * 8;  kD0 = seg0 * 16;
    kS1 = r1 * 128 + c1 * 8;  kD1 = seg1 * 16;
    int vr0 = seg0 >> 3, vp0 = seg0 & 7, vc0 = vp0 ^ (vr0 & 7);
    int vr1 = seg1 >> 3, vp1 = seg1 & 7, vc1 = vp1 ^ (vr1 & 7);
    vS0 = vr0 * 2048 + vc0 * 8;  vD0 = seg0 * 16;
    vS1 = vr1 * 2048 + vc1 * 8;  vD1 = seg1 * 16;
  }

  // stage Q [256 rows x 256B] swizzled into smem[0..65536)
#pragma unroll
  for (int it = 0; it < 8; it++) {
    int seg = t + it * 512;
    int r = seg >> 4, p = seg & 15;
    int c = (p & 8) | ((p ^ r) & 7);
    gld_lds16(Qg + r * 128 + c * 8, smem + seg * 16);
  }
  __syncthreads();
  bf16x8 qf[8];   // B-frag: Q[qrow=col][d = ks*16 + hi*8 + j]  (pre-scaled)
#pragma unroll
  for (int ks = 0; ks < 8; ks++) {
    int c = ks * 2 + hi;
    int p = (c & 8) | ((c ^ (qrow & 7)) & 7);
    qf[ks] = *(const bf16x8*)(smem + qrow * 256 + p * 16);
  }
  __syncthreads();   // all waves done reading Q (K/V bufs overlay it)

  // prologue: stage tile 0 into buffer 0
  gld_lds16(Kg + kS0, smem + kD0);
  gld_lds16(Kg + kS1, smem + kD1);
  gld_lds16(Vg + vS0, smem + 32768 + vD0);
  gld_lds16(Vg + vS1, smem + 32768 + vD1);
  __syncthreads();

  const unsigned short* kp = Kg + 8192;   // tile 1
  const unsigned short* vp = Vg + 64;     // tile 1

  f32x16 O[4];   // D[qrow(reg)][chunk = cb*32+col]
#pragma unroll
  for (int cb = 0; cb < 4; cb++)
#pragma unroll
    for (int r = 0; r < 16; r++) O[cb][r] = 0.f;
  float lp = 0.f;

  unsigned char* B0K = smem;
  unsigned char* B1K = smem + 16384;
  unsigned char* B0V = smem + 32768;
  unsigned char* B1V = smem + 49152;

#pragma unroll 1
  for (int kt2 = 0; kt2 < 16; kt2++) {
    ATTN_TILE(B0K, B0V, B1K, B1V, 1);
    ATTN_TILE(B1K, B1V, B0K, B0V, (kt2 < 15));
  }

  // lp currently = sum over this lane's 32 keys/tile; pair-lane holds the rest
  lp += __shfl_xor(lp, 32);
  float* linv_arr = (float*)smem;   // K/V dead after final barrier
  linv_arr[wv * 32 + col] = 1.f / lp;
  float4 li[4];
#pragma unroll
  for (int rq = 0; rq < 4; rq++)
    li[rq] = *(const float4*)&linv_arr[wv * 32 + rq * 8 + hi * 4];

  unsigned short* Cg = ctx + (size_t)g * 262144 + (size_t)qt * 32768;
#pragma unroll
  for (int cb = 0; cb < 4; cb++)
#pragma unroll
    for (int rq = 0; rq < 4; rq++)
#pragma unroll
      for (int j = 0; j < 4; j++) {
        int row = wv * 32 + rq * 8 + hi * 4 + j;
        Cg[(size_t)row * 128 + cb * 32 + col] = f2bf(O[cb][rq * 4 + j] * li[rq][j]);
      }
}

// ---------- kernel 5: output projection + bias + residual ----------
__global__ __launch_bounds__(256) void gemm_proj_kernel(
    const unsigned short* __restrict__ A,
    const unsigned short* __restrict__ W,
    const float* __restrict__ bp,
    const float* __restrict__ qres,
    float* __restrict__ out) {
  __shared__ unsigned short Alds[128 * 32];
  __shared__ unsigned short Blds[128 * 32];
  const int t   = threadIdx.x;
  const int bid = blockIdx.x;
  const int tn  = bid % 8;
  const int tm  = bid / 8;
  const unsigned short* Bptr = W + (size_t)tn * 128 * 1024;

  const int lane = t & 63;
  const int wv   = t >> 6;
  const int wm   = (wv >> 1) * 64;
  const int wn   = (wv & 1) * 64;
  const int fr   = lane & 15;
  const int kq   = (lane >> 4) * 8;

  f32x4 acc[4][4];
#pragma unroll
  for (int i = 0; i < 4; i++)
#pragma unroll
    for (int j = 0; j < 4; j++) acc[i][j] = (f32x4){0.f, 0.f, 0.f, 0.f};

  const int sr = t >> 2;
  const int sc = (t & 3) << 3;
  const unsigned short* gA = A + (size_t)(tm * 128 + sr) * 1024 + sc;
  const unsigned short* gB = Bptr + (size_t)sr * 1024 + sc;
  unsigned short* lA = Alds + t * 8;
  unsigned short* lB = Blds + t * 8;

  for (int k0 = 0; k0 < 1024; k0 += 32) {
    gld_lds16(gA, lA);
    gld_lds16(gA + 64 * 1024, lA + 64 * 32);
    gld_lds16(gB, lB);
    gld_lds16(gB + 64 * 1024, lB + 64 * 32);
    gA += 32; gB += 32;
    __syncthreads();
    bf16x8 af[4], bfr[4];
#pragma unroll
    for (int i = 0; i < 4; i++) {
      af[i]  = *(const bf16x8*)&Alds[(wm + i * 16 + fr) * 32 + kq];
      bfr[i] = *(const bf16x8*)&Blds[(wn + i * 16 + fr) * 32 + kq];
    }
#pragma unroll
    for (int i = 0; i < 4; i++)
#pragma unroll
      for (int j = 0; j < 4; j++)
        acc[i][j] = __builtin_amdgcn_mfma_f32_16x16x32_bf16(af[i], bfr[j], acc[i][j], 0, 0, 0);
    __syncthreads();
  }

  const int quad = lane >> 4;
  const int cc   = lane & 15;
#pragma unroll
  for (int i = 0; i < 4; i++)
#pragma unroll
    for (int j = 0; j < 4; j++)
#pragma unroll
      for (int r = 0; r < 4; r++) {
        int row = tm * 128 + wm + i * 16 + quad * 4 + r;
        int col = tn * 128 + wn + j * 16 + cc;
        out[(size_t)row * 1024 + col] =
            acc[i][j][r] + bp[col] + qres[(size_t)row * 1024 + col];
      }
}

// ---------- kernel 6: in-place LayerNorm ----------
__global__ __launch_bounds__(256) void ln_kernel(float* __restrict__ out,
                                                 const float* __restrict__ gamma,
                                                 const float* __restrict__ beta) {
  __shared__ float red[8];
  const int row = blockIdx.x;
  float* p = out + (size_t)row * 1024;
  const int t = threadIdx.x;
  float4 v = ((const float4*)p)[t];
  float s  = v.x + v.y + v.z + v.w;
  float s2 = v.x * v.x + v.y * v.y + v.z * v.z + v.w * v.w;
#pragma unroll
  for (int off = 1; off < 64; off <<= 1) {
    s  += __shfl_xor(s, off);
    s2 += __shfl_xor(s2, off);
  }
  const int wv = t >> 6;
  if ((t & 63) == 0) { red[wv] = s; red[4 + wv] = s2; }
  __syncthreads();
  float S  = red[0] + red[1] + red[2] + red[3];
  float S2 = red[4] + red[5] + red[6] + red[7];
  float mu  = S * (1.f / 1024.f);
  float var = S2 * (1.f / 1024.f) - mu * mu;
  float rstd = rsqrtf(var + 1e-5f);
  float4 gm = ((const float4*)gamma)[t];
  float4 bt = ((const float4*)beta)[t];
  v.x = (v.x - mu) * rstd * gm.x + bt.x;
  v.y = (v.y - mu) * rstd * gm.y + bt.y;
  v.z = (v.z - mu) * rstd * gm.z + bt.z;
  v.w = (v.w - mu) * rstd * gm.w + bt.w;
  ((float4*)p)[t] = v;
}

// ---------- launch ----------
extern "C" void kernel_launch(void* const* d_in, const int* in_sizes, int n_in,
                              void* d_out, int out_size, void* d_ws, size_t ws_size,
                              hipStream_t stream) {
  const float* query = (const float*)d_in[0];
  const float* keys  = (const float*)d_in[1];
  const float* Wq    = (const float*)d_in[2];
  const float* Wk    = (const float*)d_in[3];
  const float* Wv    = (const float*)d_in[4];
  const float* Wp    = (const float*)d_in[5];
  const float* bp    = (const float*)d_in[6];
  const float* gamma = (const float*)d_in[7];
  const float* beta  = (const float*)d_in[8];
  float* out = (float*)d_out;

  unsigned short* ws   = (unsigned short*)d_ws;
  unsigned short* qb   = ws;                 // 16777216
  unsigned short* kb   = ws + 16777216;      // 16777216
  unsigned short* Wqkv = ws + 33554432;      // 3145728
  unsigned short* Wpb  = ws + 36700160;      // 1048576
  unsigned short* Qb   = ws + 37748736;      // 16777216
  unsigned short* Kb   = ws + 54525952;      // 16777216
  unsigned short* Vb   = ws + 71303168;      // 16777216
  unsigned short* Vtb  = kb;                 // reuse (kb dead after QKV GEMM)
  unsigned short* ctx  = qb;                 // reuse (qb dead after QKV GEMM)

  convert_kernel<<<36864, 256, 0, stream>>>(query, keys, Wq, Wk, Wv, Wp, qb, kb, Wqkv, Wpb);
  gemm_qkv8_kernel<<<768, 512, 0, stream>>>(qb, kb, Wqkv, Qb, Kb, Vb);
  vtrans_kernel<<<1024, 256, 0, stream>>>(Vb, Vtb);
  attn_kernel<<<512, 512, 0, stream>>>(Qb, Kb, Vtb, ctx);
  gemm_proj_kernel<<<1024, 256, 0, stream>>>(ctx, Wpb, bp, query, out);
  ln_kernel<<<16384, 256, 0, stream>>>(out, gamma, beta);
}

// Round 7
// 507.065 us; speedup vs baseline: 1.8014x; 1.0328x over previous
//
#include <hip/hip_runtime.h>

typedef __bf16 bf16x8 __attribute__((ext_vector_type(8)));
typedef float f32x4 __attribute__((ext_vector_type(4)));
typedef float f32x16 __attribute__((ext_vector_type(16)));
typedef unsigned uint2e __attribute__((ext_vector_type(2)));

#define SCLOG 0.04508422f   // (1024^-0.5) * log2(e)

// ---------- helpers ----------
__device__ __forceinline__ unsigned short f2bf(float f) {
  union { float f; unsigned int u; } v;
  v.f = f;
  unsigned int u = v.u;
  u += 0x7fffu + ((u >> 16) & 1u);   // RNE
  return (unsigned short)(u >> 16);
}

__device__ __forceinline__ void gld_lds16(const void* g, void* l) {
  __builtin_amdgcn_global_load_lds(
      (const __attribute__((address_space(1))) void*)g,
      (__attribute__((address_space(3))) void*)l, 16, 0, 0);
}

// ---------- kernel 1: fp32 -> bf16 conversion ----------
__global__ __launch_bounds__(256) void convert_kernel(
    const float* __restrict__ q, const float* __restrict__ k,
    const float* __restrict__ wq, const float* __restrict__ wk,
    const float* __restrict__ wv, const float* __restrict__ wp,
    unsigned short* __restrict__ qb, unsigned short* __restrict__ kb,
    unsigned short* __restrict__ Wqkv, unsigned short* __restrict__ Wpb) {
  size_t i = (size_t)blockIdx.x * 256 + threadIdx.x;
  const float* src; unsigned short* dst; size_t off;
  if (i < 4194304)      { src = q;  dst = qb;             off = i; }
  else if (i < 8388608) { src = k;  dst = kb;             off = i - 4194304; }
  else if (i < 8650752) { src = wq; dst = Wqkv;           off = i - 8388608; }
  else if (i < 8912896) { src = wk; dst = Wqkv + 1048576; off = i - 8650752; }
  else if (i < 9175040) { src = wv; dst = Wqkv + 2097152; off = i - 8912896; }
  else                  { src = wp; dst = Wpb;            off = i - 9175040; }
  float4 v = ((const float4*)src)[off];
  ushort4 o;
  o.x = f2bf(v.x); o.y = f2bf(v.y); o.z = f2bf(v.z); o.w = f2bf(v.w);
  ((ushort4*)dst)[off] = o;
}

// ---------- shared 8-phase GEMM machinery ----------
#define QKV_BAR __builtin_amdgcn_s_barrier()
#define QKV_LGKM asm volatile("s_waitcnt lgkmcnt(0)" ::: "memory")

#define QKV_STG(lc, h, srcb, s)                                               \
  gld_lds16((srcb) + (size_t)(s) * 128 + gro0, (lc) + (h) * 16384 + d0);      \
  gld_lds16((srcb) + (size_t)(s) * 128 + gro1, (lc) + (h) * 16384 + d0 + 1024);

#define QKV_RDA(I0)                                                           \
  _Pragma("unroll") for (int i4 = 0; i4 < 4; ++i4) {                          \
    af[i4][0] = *(const bf16x8*)(tb + rbA + ((I0) + i4) * 2048 + cx0);        \
    af[i4][1] = *(const bf16x8*)(tb + rbA + ((I0) + i4) * 2048 + cx1);        \
  }

#define QKV_RDB(JP)                                                           \
  _Pragma("unroll") for (int j2 = 0; j2 < 2; ++j2) {                          \
    bfr[JP][j2][0] = *(const bf16x8*)(tb + rbB + ((JP) * 2 + j2) * 2048 + cx0); \
    bfr[JP][j2][1] = *(const bf16x8*)(tb + rbB + ((JP) * 2 + j2) * 2048 + cx1); \
  }

#define QKV_MM(I0, JP)                                                        \
  _Pragma("unroll") for (int i4 = 0; i4 < 4; ++i4)                            \
  _Pragma("unroll") for (int j2 = 0; j2 < 2; ++j2)                            \
  _Pragma("unroll") for (int kk = 0; kk < 2; ++kk)                            \
    acc[(I0) + i4][(JP) * 2 + j2] = __builtin_amdgcn_mfma_f32_16x16x32_bf16(  \
        af[i4][kk], bfr[JP][j2][kk], acc[(I0) + i4][(JP) * 2 + j2], 0, 0, 0);

// K-loop body (16 iterations, BK=64, double-buffered 128KB LDS)
#define QKV_KLOOP                                                             \
  _Pragma("unroll")                                                           \
  for (int s = 0; s < 2; ++s) {                                               \
    char* lc = lds + s * 65536;                                               \
    QKV_STG(lc, 0, aBase, s);                                                 \
    QKV_STG(lc, 1, aBase + 262144, s);                                        \
    QKV_STG(lc + 32768, 0, bBase, s);                                         \
    QKV_STG(lc + 32768, 1, bBase + 262144, s);                                \
  }                                                                           \
  asm volatile("s_waitcnt vmcnt(8)" ::: "memory");                            \
  QKV_BAR;                                                                    \
  _Pragma("unroll 1")                                                         \
  for (int kt = 0; kt < 16; ++kt) {                                           \
    const char* tb = lds + (kt & 1) * 65536;                                  \
    char* lc = lds + (kt & 1) * 65536;                                        \
    const int s = kt + 2;                                                     \
    bf16x8 af[4][2], bfr[2][2][2];                                            \
    QKV_RDA(0);                                                               \
    QKV_RDB(0);                                                               \
    QKV_BAR; QKV_LGKM;                                                        \
    __builtin_amdgcn_s_setprio(1);                                            \
    QKV_MM(0, 0);                                                             \
    __builtin_amdgcn_s_setprio(0);                                            \
    QKV_BAR;                                                                  \
    QKV_RDB(1);                                                               \
    QKV_BAR; QKV_LGKM;                                                        \
    __builtin_amdgcn_s_setprio(1);                                            \
    QKV_MM(0, 1);                                                             \
    __builtin_amdgcn_s_setprio(0);                                            \
    QKV_BAR;                                                                  \
    QKV_RDA(4);                                                               \
    if (s < 16) {                                                             \
      QKV_STG(lc + 32768, 0, bBase, s);                                       \
      QKV_STG(lc + 32768, 1, bBase + 262144, s);                              \
    }                                                                         \
    QKV_BAR; QKV_LGKM;                                                        \
    __builtin_amdgcn_s_setprio(1);                                            \
    QKV_MM(4, 1);                                                             \
    __builtin_amdgcn_s_setprio(0);                                            \
    QKV_BAR;                                                                  \
    if (s < 16) {                                                             \
      QKV_STG(lc, 0, aBase, s);                                               \
      QKV_STG(lc, 1, aBase + 262144, s);                                      \
    }                                                                         \
    QKV_BAR;                                                                  \
    __builtin_amdgcn_s_setprio(1);                                            \
    QKV_MM(4, 0);                                                             \
    __builtin_amdgcn_s_setprio(0);                                            \
    if (kt <= 13)      { asm volatile("s_waitcnt vmcnt(8)" ::: "memory"); }   \
    else if (kt == 14) { asm volatile("s_waitcnt vmcnt(0)" ::: "memory"); }   \
    if (kt < 15) QKV_BAR;                                                     \
  }

#define QKV_COMMON_DECLS                                                      \
  const int t = threadIdx.x;                                                  \
  const int lane = t & 63;                                                    \
  const int w = t >> 6;                                                       \
  const int fr = lane & 15;                                                   \
  const int quad = lane >> 4;                                                 \
  const int wm2 = w >> 2, wn4 = w & 3;                                        \
  const size_t gro0 = (size_t)(w * 16 + (lane >> 3)) * 2048 +                 \
                      (size_t)(((lane & 7) ^ (lane >> 3)) << 4);              \
  const size_t gro1 = gro0 + 8 * 2048;                                        \
  const int d0 = w * 2048 + lane * 16;                                        \
  const int rbA = (wm2 * 128 + fr) * 128;                                     \
  const int rbB = 32768 + (wn4 * 64 + fr) * 128;                              \
  const int cx0 = (quad * 16) ^ ((fr & 7) << 4);                              \
  const int cx1 = cx0 ^ 64;

// ---------- kernel 2: fused QKV GEMM (8-phase 256x256) ----------
__global__ __launch_bounds__(512, 2) void gemm_qkv8_kernel(
    const unsigned short* __restrict__ qb,
    const unsigned short* __restrict__ kb,
    const unsigned short* __restrict__ W,       // [3072][1024]
    unsigned short* __restrict__ Qo,
    unsigned short* __restrict__ Ko,
    unsigned short* __restrict__ Vo) {
  __shared__ char lds[131072];
  QKV_COMMON_DECLS

  const int orig = blockIdx.x;
  const int sseq = orig >> 3;                  // 0..95
  const int tn = sseq >> 3;                    // 0..11
  const int tm = (orig & 7) * 8 + (sseq & 7);  // 0..63

  const unsigned short* Ap = (tn < 4) ? qb : kb;
  const char* aBase = (const char*)Ap + (size_t)(tm * 256) * 2048;
  const char* bBase = (const char*)W + (size_t)(tn * 256) * 2048;

  f32x4 acc[8][4];
#pragma unroll
  for (int i = 0; i < 8; ++i)
#pragma unroll
    for (int j = 0; j < 4; ++j) acc[i][j] = (f32x4){0.f, 0.f, 0.f, 0.f};

  QKV_KLOOP

  const int sel = tn >> 2;  // 0=Q 1=K 2=V
  unsigned short* Out = sel == 0 ? Qo : (sel == 1 ? Ko : Vo);
  const float osc = (sel == 0) ? SCLOG : 1.f;
  const int row0 = tm * 256 + wm2 * 128 + quad * 4;
  const int col0 = (tn & 3) * 256 + wn4 * 64 + fr;
#pragma unroll
  for (int i = 0; i < 8; ++i)
#pragma unroll
    for (int j = 0; j < 4; ++j)
#pragma unroll
      for (int r = 0; r < 4; ++r)
        Out[(size_t)(row0 + i * 16 + r) * 1024 + col0 + j * 16] = f2bf(acc[i][j][r] * osc);
}

// ---------- kernel 5 v2: output projection (8-phase 256x256) + bias + residual ----------
__global__ __launch_bounds__(512, 2) void gemm_proj8_kernel(
    const unsigned short* __restrict__ A,       // ctx bf16 [16384][1024]
    const unsigned short* __restrict__ W,       // Wp bf16 [1024][1024]
    const float* __restrict__ bp,
    const float* __restrict__ qres,
    float* __restrict__ out) {
  __shared__ char lds[131072];
  QKV_COMMON_DECLS

  // 256 blocks = 8 xcd * 32; tn 0..3, tm 0..63 (bijective)
  const int orig = blockIdx.x;
  const int sseq = orig >> 3;                  // 0..31
  const int tn = sseq >> 3;                    // 0..3
  const int tm = (orig & 7) * 8 + (sseq & 7);  // 0..63

  const char* aBase = (const char*)A + (size_t)(tm * 256) * 2048;
  const char* bBase = (const char*)W + (size_t)(tn * 256) * 2048;

  f32x4 acc[8][4];
#pragma unroll
  for (int i = 0; i < 8; ++i)
#pragma unroll
    for (int j = 0; j < 4; ++j) acc[i][j] = (f32x4){0.f, 0.f, 0.f, 0.f};

  QKV_KLOOP

  const int row0 = tm * 256 + wm2 * 128 + quad * 4;
  const int col0 = tn * 256 + wn4 * 64 + fr;
#pragma unroll
  for (int i = 0; i < 8; ++i)
#pragma unroll
    for (int j = 0; j < 4; ++j) {
      const int col = col0 + j * 16;
      const float bpc = bp[col];
#pragma unroll
      for (int r = 0; r < 4; ++r) {
        const size_t idx = (size_t)(row0 + i * 16 + r) * 1024 + col;
        out[idx] = acc[i][j][r] + bpc + qres[idx];
      }
    }
}

// ---------- kernel 3: per-group V transpose ----------
__global__ __launch_bounds__(256) void vtrans_kernel(
    const unsigned short* __restrict__ V, unsigned short* __restrict__ Vt) {
  __shared__ unsigned short T[128 * 136];
  const int g  = blockIdx.x >> 4;
  const int kt = blockIdx.x & 15;
  const unsigned short* Vg = V + (size_t)g * 262144 + (size_t)kt * 128 * 128;
  unsigned short* Vtg = Vt + (size_t)g * 262144 + kt * 128;
  const int t = threadIdx.x;
#pragma unroll
  for (int it = 0; it < 8; it++) {
    int seg = t + it * 256;
    int k  = seg >> 4;
    int c8 = (seg & 15) << 3;
    uint4 a = *(const uint4*)(Vg + k * 128 + c8);
    unsigned short* Tp = &T[c8 * 136 + k];
    Tp[0 * 136] = (unsigned short)(a.x & 0xffff);
    Tp[1 * 136] = (unsigned short)(a.x >> 16);
    Tp[2 * 136] = (unsigned short)(a.y & 0xffff);
    Tp[3 * 136] = (unsigned short)(a.y >> 16);
    Tp[4 * 136] = (unsigned short)(a.z & 0xffff);
    Tp[5 * 136] = (unsigned short)(a.z >> 16);
    Tp[6 * 136] = (unsigned short)(a.w & 0xffff);
    Tp[7 * 136] = (unsigned short)(a.w >> 16);
  }
  __syncthreads();
#pragma unroll
  for (int it = 0; it < 8; it++) {
    int seg = t + it * 256;
    int c  = seg >> 4;
    int k8 = (seg & 15) << 3;
    uint4 o = *(const uint4*)&T[c * 136 + k8];
    *(uint4*)(Vtg + (size_t)c * 2048 + k8) = o;
  }
}

// ---------- kernel 4 v7: flash attention, 32x32 MFMA, in-register P ----------
// v7 = v6 with widened LDS XOR swizzles (bank-conflict fix):
//   K/Q rows (16 slots): slot = c ^ (row&15)   (was 8-slot -> 4-way conflict)
//   V rows   (8 slots):  slot = c ^ (row&7) ^ ((row>>3)&1)
// Applied on BOTH sides (pre-swizzled global source + read offsets).
#define PACK_HALF(EX, KSBASE)                                                  \
    _Pragma("unroll")                                                          \
    for (int c2 = 0; c2 < 2; c2++)                                             \
      _Pragma("unroll")                                                        \
      for (int e = 0; e < 2; e++) {                                            \
        unsigned ua, ub;                                                       \
        asm("v_cvt_pk_bf16_f32 %0, %1, %2" : "=v"(ua)                          \
            : "v"(EX[8 * c2 + 2 * e]), "v"(EX[8 * c2 + 2 * e + 1]));           \
        asm("v_cvt_pk_bf16_f32 %0, %1, %2" : "=v"(ub)                          \
            : "v"(EX[8 * c2 + 4 + 2 * e]), "v"(EX[8 * c2 + 4 + 2 * e + 1]));   \
        uint2e rr = __builtin_amdgcn_permlane32_swap(ua, ub, false, false);    \
        if (e == 0) { paw[(KSBASE) + c2].x = rr[0]; paw[(KSBASE) + c2].z = rr[1]; } \
        else        { paw[(KSBASE) + c2].y = rr[0]; paw[(KSBASE) + c2].w = rr[1]; } \
      }

#define ATTN_TILE(KSH, VSH, KST, VST, PREF)                                    \
  {                                                                            \
    if (PREF) {                                                                \
      gld_lds16(kp + kS0, (KST) + kD0);                                        \
      gld_lds16(kp + kS1, (KST) + kD1);                                        \
      gld_lds16(vp + vS0, (VST) + vD0);                                        \
      gld_lds16(vp + vS1, (VST) + vD1);                                        \
      kp += 8192; vp += 64;                                                    \
    }                                                                          \
    f32x16 s0, s1;                                                             \
    _Pragma("unroll")                                                          \
    for (int r = 0; r < 16; r++) { s0[r] = 0.f; s1[r] = 0.f; }                 \
    {                                                                          \
      bf16x8 kf[8];                                                            \
      _Pragma("unroll")                                                        \
      for (int ks = 0; ks < 8; ks++)                                           \
        kf[ks] = *(const bf16x8*)((KSH) + kb0 + kOf[ks]);                      \
      _Pragma("unroll")                                                        \
      for (int ks = 0; ks < 8; ks++)                                           \
        s0 = __builtin_amdgcn_mfma_f32_32x32x16_bf16(kf[ks], qf[ks], s0, 0, 0, 0); \
    }                                                                          \
    {                                                                          \
      bf16x8 kf[8];                                                            \
      _Pragma("unroll")                                                        \
      for (int ks = 0; ks < 8; ks++)                                           \
        kf[ks] = *(const bf16x8*)((KSH) + kb0 + 8192 + kOf[ks]);               \
      _Pragma("unroll")                                                        \
      for (int ks = 0; ks < 8; ks++)                                           \
        s1 = __builtin_amdgcn_mfma_f32_32x32x16_bf16(kf[ks], qf[ks], s1, 0, 0, 0); \
    }                                                                          \
    float ex0[16], ex1[16];                                                    \
    _Pragma("unroll")                                                          \
    for (int r = 0; r < 16; r++) {                                             \
      ex0[r] = __builtin_amdgcn_exp2f(fminf(s0[r], 30.f));                     \
      ex1[r] = __builtin_amdgcn_exp2f(fminf(s1[r], 30.f));                     \
      lp += ex0[r] + ex1[r];                                                   \
    }                                                                          \
    uint4 paw[4];                                                              \
    PACK_HALF(ex0, 0)                                                          \
    PACK_HALF(ex1, 2)                                                          \
    _Pragma("unroll")                                                          \
    for (int cb = 0; cb < 4; cb++) {                                           \
      _Pragma("unroll")                                                        \
      for (int ks = 0; ks < 4; ks++) {                                         \
        bf16x8 vf = *(const bf16x8*)((VSH) + cb * 4096 + vOf[ks]);             \
        bf16x8 pa8 = __builtin_bit_cast(bf16x8, paw[ks]);                      \
        O[cb] = __builtin_amdgcn_mfma_f32_32x32x16_bf16(pa8, vf, O[cb], 0, 0, 0); \
      }                                                                        \
    }                                                                          \
    __syncthreads();                                                           \
  }

__global__ __launch_bounds__(512, 1) void attn_kernel(
    const unsigned short* __restrict__ Q,
    const unsigned short* __restrict__ K,
    const unsigned short* __restrict__ Vt,   // bf16 [64 grp][128 chunk][2048 key]
    unsigned short* __restrict__ ctx) {
  __shared__ unsigned char smem[65536];

  const int bid = blockIdx.x;
  const int g  = (bid & 7) * 8 + (bid >> 6);     // bijective XCD swizzle (512=8*64)
  const int qt = (bid >> 3) & 7;
  const unsigned short* Qg = Q + (size_t)g * 262144 + (size_t)qt * 32768;
  const unsigned short* Kg = K + (size_t)g * 262144;
  const unsigned short* Vg = Vt + (size_t)g * 262144;   // [128][2048]

  const int t    = threadIdx.x;
  const int lane = t & 63;
  const int wv   = t >> 6;          // wave owns qrows [wv*32, wv*32+32)
  const int col  = lane & 31;
  const int hi   = lane >> 5;
  const int qrow = wv * 32 + col;

  // loop-invariant swizzled LDS offsets (v7 swizzles)
  int kOf[8];
#pragma unroll
  for (int ks = 0; ks < 8; ks++) {
    int c = ks * 2 + hi;
    kOf[ks] = (c ^ (col & 15)) << 4;
  }
  const int kb0 = col * 256;
  int vOf[4];
#pragma unroll
  for (int ks = 0; ks < 4; ks++) {
    int c = ks * 2 + hi;
    vOf[ks] = col * 128 + (((c ^ (col & 7) ^ ((col >> 3) & 1)) & 7) << 4);
  }
  int kS0, kS1, kD0, kD1, vS0, vS1, vD0, vD1;
  {
    int seg0 = t, seg1 = t + 512;
    int r0 = seg0 >> 4, p0 = seg0 & 15;
    int r1 = seg1 >> 4, p1 = seg1 & 15;
    kS0 = r0 * 128 + (p0 ^ (r0 & 15)) * 8;  kD0 = seg0 * 16;
    kS1 = r1 * 128 + (p1 ^ (r1 & 15)) * 8;  kD1 = seg1 * 16;
    int vr0 = seg0 >> 3, vp0 = seg0 & 7;
    int vr1 = seg1 >> 3, vp1 = seg1 & 7;
    vS0 = vr0 * 2048 + ((vp0 ^ (vr0 & 7) ^ ((vr0 >> 3) & 1)) & 7) * 8;  vD0 = seg0 * 16;
    vS1 = vr1 * 2048 + ((vp1 ^ (vr1 & 7) ^ ((vr1 >> 3) & 1)) & 7) * 8;  vD1 = seg1 * 16;
  }

  // stage Q [256 rows x 256B] swizzled into smem[0..65536)
#pragma unroll
  for (int it = 0; it < 8; it++) {
    int seg = t + it * 512;
    int r = seg >> 4, p = seg & 15;
    int c = p ^ (r & 15);
    gld_lds16(Qg + r * 128 + c * 8, smem + seg * 16);
  }
  __syncthreads();
  bf16x8 qf[8];   // B-frag: Q[qrow][d = ks*16 + hi*8 + j]  (pre-scaled)
#pragma unroll
  for (int ks = 0; ks < 8; ks++) {
    int c = ks * 2 + hi;
    int p = c ^ (qrow & 15);
    qf[ks] = *(const bf16x8*)(smem + qrow * 256 + p * 16);
  }
  __syncthreads();   // all waves done reading Q (K/V bufs overlay it)

  // prologue: stage tile 0 into buffer 0
  gld_lds16(Kg + kS0, smem + kD0);
  gld_lds16(Kg + kS1, smem + kD1);
  gld_lds16(Vg + vS0, smem + 32768 + vD0);
  gld_lds16(Vg + vS1, smem + 32768 + vD1);
  __syncthreads();

  const unsigned short* kp = Kg + 8192;   // tile 1
  const unsigned short* vp = Vg + 64;     // tile 1

  f32x16 O[4];   // D[qrow(reg)][chunk = cb*32+col]
#pragma unroll
  for (int cb = 0; cb < 4; cb++)
#pragma unroll
    for (int r = 0; r < 16; r++) O[cb][r] = 0.f;
  float lp = 0.f;

  unsigned char* B0K = smem;
  unsigned char* B1K = smem + 16384;
  unsigned char* B0V = smem + 32768;
  unsigned char* B1V = smem + 49152;

#pragma unroll 1
  for (int kt2 = 0; kt2 < 16; kt2++) {
    ATTN_TILE(B0K, B0V, B1K, B1V, 1);
    ATTN_TILE(B1K, B1V, B0K, B0V, (kt2 < 15));
  }

  // lp currently = sum over this lane's 32 keys/tile; pair-lane holds the rest
  lp += __shfl_xor(lp, 32);
  float* linv_arr = (float*)smem;   // K/V dead after final barrier
  linv_arr[wv * 32 + col] = 1.f / lp;
  float4 li[4];
#pragma unroll
  for (int rq = 0; rq < 4; rq++)
    li[rq] = *(const float4*)&linv_arr[wv * 32 + rq * 8 + hi * 4];

  unsigned short* Cg = ctx + (size_t)g * 262144 + (size_t)qt * 32768;
#pragma unroll
  for (int cb = 0; cb < 4; cb++)
#pragma unroll
    for (int rq = 0; rq < 4; rq++)
#pragma unroll
      for (int j = 0; j < 4; j++) {
        int row = wv * 32 + rq * 8 + hi * 4 + j;
        Cg[(size_t)row * 128 + cb * 32 + col] = f2bf(O[cb][rq * 4 + j] * li[rq][j]);
      }
}

// ---------- kernel 6: in-place LayerNorm ----------
__global__ __launch_bounds__(256) void ln_kernel(float* __restrict__ out,
                                                 const float* __restrict__ gamma,
                                                 const float* __restrict__ beta) {
  __shared__ float red[8];
  const int row = blockIdx.x;
  float* p = out + (size_t)row * 1024;
  const int t = threadIdx.x;
  float4 v = ((const float4*)p)[t];
  float s  = v.x + v.y + v.z + v.w;
  float s2 = v.x * v.x + v.y * v.y + v.z * v.z + v.w * v.w;
#pragma unroll
  for (int off = 1; off < 64; off <<= 1) {
    s  += __shfl_xor(s, off);
    s2 += __shfl_xor(s2, off);
  }
  const int wv = t >> 6;
  if ((t & 63) == 0) { red[wv] = s; red[4 + wv] = s2; }
  __syncthreads();
  float S  = red[0] + red[1] + red[2] + red[3];
  float S2 = red[4] + red[5] + red[6] + red[7];
  float mu  = S * (1.f / 1024.f);
  float var = S2 * (1.f / 1024.f) - mu * mu;
  float rstd = rsqrtf(var + 1e-5f);
  float4 gm = ((const float4*)gamma)[t];
  float4 bt = ((const float4*)beta)[t];
  v.x = (v.x - mu) * rstd * gm.x + bt.x;
  v.y = (v.y - mu) * rstd * gm.y + bt.y;
  v.z = (v.z - mu) * rstd * gm.z + bt.z;
  v.w = (v.w - mu) * rstd * gm.w + bt.w;
  ((float4*)p)[t] = v;
}

// ---------- launch ----------
extern "C" void kernel_launch(void* const* d_in, const int* in_sizes, int n_in,
                              void* d_out, int out_size, void* d_ws, size_t ws_size,
                              hipStream_t stream) {
  const float* query = (const float*)d_in[0];
  const float* keys  = (const float*)d_in[1];
  const float* Wq    = (const float*)d_in[2];
  const float* Wk    = (const float*)d_in[3];
  const float* Wv    = (const float*)d_in[4];
  const float* Wp    = (const float*)d_in[5];
  const float* bp    = (const float*)d_in[6];
  const float* gamma = (const float*)d_in[7];
  const float* beta  = (const float*)d_in[8];
  float* out = (float*)d_out;

  unsigned short* ws   = (unsigned short*)d_ws;
  unsigned short* qb   = ws;                 // 16777216
  unsigned short* kb   = ws + 16777216;      // 16777216
  unsigned short* Wqkv = ws + 33554432;      // 3145728
  unsigned short* Wpb  = ws + 36700160;      // 1048576
  unsigned short* Qb   = ws + 37748736;      // 16777216
  unsigned short* Kb   = ws + 54525952;      // 16777216
  unsigned short* Vb   = ws + 71303168;      // 16777216
  unsigned short* Vtb  = kb;                 // reuse (kb dead after QKV GEMM)
  unsigned short* ctx  = qb;                 // reuse (qb dead after QKV GEMM)

  convert_kernel<<<36864, 256, 0, stream>>>(query, keys, Wq, Wk, Wv, Wp, qb, kb, Wqkv, Wpb);
  gemm_qkv8_kernel<<<768, 512, 0, stream>>>(qb, kb, Wqkv, Qb, Kb, Vb);
  vtrans_kernel<<<1024, 256, 0, stream>>>(Vb, Vtb);
  attn_kernel<<<512, 512, 0, stream>>>(Qb, Kb, Vtb, ctx);
  gemm_proj8_kernel<<<256, 512, 0, stream>>>(ctx, Wpb, bp, query, out);
  ln_kernel<<<16384, 256, 0, stream>>>(out, gamma, beta);
}